// Round 14
// baseline (424.619 us; speedup 1.0000x reference)
//
#include <hip/hip_runtime.h>
#include <cfloat>
#include <cmath>

#define NB_CODE 1024
#define CODE_DIM 64
#define NROWS (32 * 8192)          // N*T = 262144
#define NTC ((size_t)NROWS * CODE_DIM)
#define TAU 0.04f                  // ~6 sigma of single-f16-product + packing dist error

typedef __attribute__((ext_vector_type(8))) _Float16 half8;
typedef __attribute__((ext_vector_type(4))) float f32x4;

// ws layout (32-bit words):
//   0..1023      counts (u32)               [real]
//   1024         loss_sum (f32 atomic)      [real]
//   1028..2051   cnorm f32[1024]
//   2052..34819  cbp: fragment-major f16 of (-2*cb), 128 KB
//   36000..37023 sink counts (u32)          [io2 probe only]
//   37024        sink loss                  [io2 probe only]
#define W_LOSS 1024
#define W_CNORM 1028
#define W_CBP 2052
#define W_SINKC 36000
#define W_SINKL 37024

__device__ inline float unmask6(float v) {
    return __uint_as_float(__float_as_uint(v) & 0xFFFFFFC0u);
}

// ---- prep: cnorm + fragment-major f16 of (-2*codebook) ----
__global__ void prep_kernel(const float* __restrict__ cb, float* __restrict__ ws) {
    int j = blockIdx.x * blockDim.x + threadIdx.x;
    if (j >= NB_CODE) return;
    float* cnorm = ws + W_CNORM;
    half8* cbp = (half8*)(ws + W_CBP);
    const int t = j >> 4, li = j & 15;

    float c2v[CODE_DIM];
    const float4* c4 = reinterpret_cast<const float4*>(cb + (size_t)j * CODE_DIM);
    float s = 0.f;
#pragma unroll
    for (int q = 0; q < 16; ++q) {
        float4 v = c4[q];
        float e[4] = {v.x, v.y, v.z, v.w};
#pragma unroll
        for (int u = 0; u < 4; ++u) {
            s = fmaf(e[u], e[u], s);
            c2v[q * 4 + u] = -2.f * e[u];
        }
    }
    cnorm[j] = s;

#pragma unroll
    for (int f = 0; f < 2; ++f) {
#pragma unroll
        for (int lg = 0; lg < 4; ++lg) {
            half8 h8;
#pragma unroll
            for (int i = 0; i < 8; ++i)
                h8[i] = (_Float16)c2v[32 * f + 8 * lg + i];   // RNE
            cbp[(size_t)(t * 2 + f) * 64 + lg * 16 + li] = h8;
        }
    }
}

// ---- I/O probe body: exact x-load pattern + exact dequant/out-write pattern,
// K-loop removed. Indices derived from loaded data (DCE-proof, deterministic).
__device__ __forceinline__ void io_body(
    const float* __restrict__ x, const float* __restrict__ cb,
    float* __restrict__ ws, float* __restrict__ out, bool with_stats)
{
    __shared__ int lds_j[256];
    const int tid = threadIdx.x;
    const int w = tid >> 6, lane = tid & 63;
    const int lg = lane >> 4;
    const int li = lane & 15;
    const int wavebase = blockIdx.x * 256 + w * 32;

    unsigned int* sink_counts = (unsigned int*)ws + W_SINKC;
    float* sink_loss = ws + W_SINKL;

    // --- x read: identical addressing to the real prologue ---
    unsigned h[2];
    float x2sum = 0.f;
#pragma unroll
    for (int rt = 0; rt < 2; ++rt) {
        const float* xr = x + (size_t)(wavebase + rt * 16 + li) * CODE_DIM;
        unsigned acc = 0x9E3779B9u * (rt + 1);
#pragma unroll
        for (int f = 0; f < 2; ++f) {
            const float4* p = reinterpret_cast<const float4*>(xr + 32 * f + 8 * lg);
            float4 v0 = p[0], v1 = p[1];
            float e[8] = {v0.x, v0.y, v0.z, v0.w, v1.x, v1.y, v1.z, v1.w};
#pragma unroll
            for (int i = 0; i < 8; ++i) {
                x2sum = fmaf(e[i], e[i], x2sum);
                acc ^= __float_as_uint(e[i]) + (acc << 6) + (acc >> 2);
            }
        }
        h[rt] = acc;
    }

    // fold across the 4 k-groups so每 row's value is row-complete, then across li
#pragma unroll
    for (int rt = 0; rt < 2; ++rt) {
        h[rt] ^= __shfl_xor((int)h[rt], 16, 64);
        h[rt] ^= __shfl_xor((int)h[rt], 32, 64);
#pragma unroll
        for (int m = 1; m <= 8; m <<= 1) h[rt] ^= __shfl_xor((int)h[rt], m, 64);
    }

    float lsum = x2sum;
    if (li == 0) {
#pragma unroll
        for (int rt = 0; rt < 2; ++rt)
#pragma unroll
            for (int r = 0; r < 4; ++r) {
                int rowin = rt * 16 + lg * 4 + r;
                int j = (int)((h[rt] ^ (unsigned)(rowin * 2654435761u)) & 1023u);
                lds_j[w * 32 + rowin] = j;
                if (with_stats) atomicAdd(&sink_counts[j], 1u);
            }
    }
#pragma unroll
    for (int m = 32; m >= 1; m >>= 1) lsum += __shfl_down(lsum, m, 64);
    if (with_stats && lane == 0) atomicAdd(sink_loss, lsum);

    __syncthreads();

    // --- out write: identical to the real dequant (gather cb[j], coalesced) ---
    for (int it = 0; it < 8; ++it) {
        int rowin = it * 4 + lg;
        int j = lds_j[w * 32 + rowin];
        float4 v = *reinterpret_cast<const float4*>(cb + (size_t)j * CODE_DIM + li * 4);
        *reinterpret_cast<float4*>(out + (size_t)(wavebase + rowin) * CODE_DIM + li * 4) = v;
    }
}

__global__ __launch_bounds__(512) void io1_kernel(
    const float* __restrict__ x, const float* __restrict__ cb,
    float* __restrict__ ws, float* __restrict__ out)
{ io_body(x, cb, ws, out, false); }

__global__ __launch_bounds__(512) void io2_kernel(
    const float* __restrict__ x, const float* __restrict__ cb,
    float* __restrict__ ws, float* __restrict__ out)
{ io_body(x, cb, ws, out, true); }

// ---- real kernel: r13 verbatim (passed, absmax OK) ----
__global__ __launch_bounds__(512) void vq_kernel(
    const float* __restrict__ x, const float* __restrict__ cb,
    float* __restrict__ ws, float* __restrict__ out)
{
    __shared__ half8 sB[2048];        // 32 KB
    __shared__ float scn[NB_CODE];    // 4 KB
    __shared__ int lds_j[256];
    __shared__ unsigned sflag[8];

    const int tid = threadIdx.x;
    const int w = tid >> 6, lane = tid & 63;
    const int lg = lane >> 4;
    const int li = lane & 15;
    const int wavebase = blockIdx.x * 256 + w * 32;

    const float* cnorm_g = ws + W_CNORM;
    const half8* cbp = (const half8*)(ws + W_CBP);
    unsigned int* counts = (unsigned int*)ws;
    float* loss_sum = ws + W_LOSS;

#define STAGE(phx)                                                              \
    {                                                                           \
        const half8* gsrc_ = cbp + (size_t)(phx) * 2048;                        \
        _Pragma("unroll")                                                       \
        for (int k_ = 0; k_ < 4; ++k_) {                                        \
            const int o_ = k_ * 512 + w * 64;                                   \
            __builtin_amdgcn_global_load_lds(                                   \
                (const __attribute__((address_space(1))) unsigned int*)(gsrc_ + o_ + lane), \
                (__attribute__((address_space(3))) unsigned int*)&sB[o_],       \
                16, 0, 0);                                                      \
        }                                                                       \
    }

    STAGE(0);

    half8 xh[2][2];
    float x2sum = 0.f;
#pragma unroll
    for (int rt = 0; rt < 2; ++rt) {
        const float* xr = x + (size_t)(wavebase + rt * 16 + li) * CODE_DIM;
#pragma unroll
        for (int f = 0; f < 2; ++f) {
            const float4* p = reinterpret_cast<const float4*>(xr + 32 * f + 8 * lg);
            float4 v0 = p[0], v1 = p[1];
            float e[8] = {v0.x, v0.y, v0.z, v0.w, v1.x, v1.y, v1.z, v1.w};
            half8 h8;
#pragma unroll
            for (int i = 0; i < 8; ++i) {
                float xe = e[i];
                x2sum = fmaf(xe, xe, x2sum);
                h8[i] = (_Float16)xe;
            }
            xh[rt][f] = h8;
        }
    }
    for (int i = tid; i < NB_CODE; i += 512) scn[i] = cnorm_g[i];
    if (tid < 8) sflag[tid] = 0u;

    asm volatile("s_waitcnt vmcnt(0)" ::: "memory");
    __builtin_amdgcn_sched_barrier(0);
    __syncthreads();

    float best[2][4], second[2][4];
#pragma unroll
    for (int rt = 0; rt < 2; ++rt)
#pragma unroll
        for (int r = 0; r < 4; ++r) { best[rt][r] = FLT_MAX; second[rt][r] = FLT_MAX; }

    for (int ph = 0; ph < 4; ++ph) {
        for (int tl = 0; tl < 16; ++tl) {
            const int T = ph * 16 + tl;
            half8 b0 = sB[tl * 128 + lane];
            half8 b1 = sB[tl * 128 + 64 + lane];
            float cn = scn[T * 16 + li];
            f32x4 ci = {cn, cn, cn, cn};
#pragma unroll
            for (int rt = 0; rt < 2; ++rt) {
                f32x4 acc = __builtin_amdgcn_mfma_f32_16x16x32_f16(xh[rt][0], b0, ci, 0, 0, 0);
                acc = __builtin_amdgcn_mfma_f32_16x16x32_f16(xh[rt][1], b1, acc, 0, 0, 0);
#pragma unroll
                for (int r = 0; r < 4; ++r) {
                    float p = __uint_as_float((__float_as_uint(acc[r]) & 0xFFFFFFC0u) | (unsigned)T);
                    second[rt][r] = fminf(second[rt][r], fmaxf(best[rt][r], p));
                    best[rt][r] = fminf(best[rt][r], p);
                }
            }
        }
        if (ph < 3) {
            __syncthreads();
            STAGE(ph + 1);
            asm volatile("s_waitcnt vmcnt(0)" ::: "memory");
            __builtin_amdgcn_sched_barrier(0);
            __syncthreads();
        }
    }
#undef STAGE

#pragma unroll
    for (int rt = 0; rt < 2; ++rt)
#pragma unroll
        for (int r = 0; r < 4; ++r) {
            float b = best[rt][r], s = second[rt][r];
            int code = ((int)(__float_as_uint(b) & 63u) << 4) | li;
#pragma unroll
            for (int m = 1; m <= 8; m <<= 1) {
                float ob = __shfl_xor(b, m, 64);
                float os = __shfl_xor(s, m, 64);
                int   oc = __shfl_xor(code, m, 64);
                s = fminf(fminf(s, os), fmaxf(b, ob));
                bool take = (ob < b) || (ob == b && oc < code);
                if (take) { b = ob; code = oc; }
            }
            best[rt][r] = b; second[rt][r] = s;
            if (li == 0) {
                int rowin = rt * 16 + lg * 4 + r;
                lds_j[w * 32 + rowin] = code;
            }
        }

    float lsum = x2sum;
    if (li == 0) {
        unsigned bits = 0;
#pragma unroll
        for (int rt = 0; rt < 2; ++rt)
#pragma unroll
            for (int r = 0; r < 4; ++r) {
                int rowin = rt * 16 + lg * 4 + r;
                int j = lds_j[w * 32 + rowin];
                atomicAdd(&counts[j], 1u);
                float bd = unmask6(best[rt][r]);
                lsum += bd;
                if (unmask6(second[rt][r]) - bd <= TAU) bits |= 1u << rowin;
            }
        if (bits) atomicOr(&sflag[w], bits);
    }
#pragma unroll
    for (int m = 32; m >= 1; m >>= 1) lsum += __shfl_down(lsum, m, 64);
    if (lane == 0) atomicAdd(loss_sum, lsum);

    __syncthreads();

    unsigned fm = sflag[w];
    while (fm) {
        const int row = __ffs(fm) - 1;
        fm &= fm - 1;
        const int rowg = wavebase + row;

        float xr[CODE_DIM];
        const float4* x4 = reinterpret_cast<const float4*>(x + (size_t)rowg * CODE_DIM);
#pragma unroll
        for (int q = 0; q < 16; ++q) {
            float4 v = x4[q];
            xr[4 * q + 0] = v.x; xr[4 * q + 1] = v.y;
            xr[4 * q + 2] = v.z; xr[4 * q + 3] = v.w;
        }
        float bestv = FLT_MAX; int bj = 0x7fffffff;
        for (int t = 0; t < 16; ++t) {
            int j = lane * 16 + t;
            const float* c = cb + (size_t)j * CODE_DIM;
            float d0 = 0.f, d1 = 0.f, d2 = 0.f, d3 = 0.f;
#pragma unroll
            for (int k = 0; k < CODE_DIM; k += 4) {
                d0 = fmaf(xr[k + 0], c[k + 0], d0);
                d1 = fmaf(xr[k + 1], c[k + 1], d1);
                d2 = fmaf(xr[k + 2], c[k + 2], d2);
                d3 = fmaf(xr[k + 3], c[k + 3], d3);
            }
            float dist = fmaf(-2.f, (d0 + d1) + (d2 + d3), scn[j]);
            if (dist < bestv) { bestv = dist; bj = j; }
        }
#pragma unroll
        for (int m = 1; m <= 32; m <<= 1) {
            float ob = __shfl_xor(bestv, m, 64);
            int   oj = __shfl_xor(bj, m, 64);
            bool take = (ob < bestv) || (ob == bestv && oj < bj);
            if (take) { bestv = ob; bj = oj; }
        }
        if (lane == 0) {
            int old = lds_j[w * 32 + row];
            if (bj != old) {
                lds_j[w * 32 + row] = bj;
                atomicAdd(&counts[bj], 1u);
                atomicAdd(&counts[old], (unsigned)-1);
            }
        }
    }

    for (int it = 0; it < 8; ++it) {
        int rowin = it * 4 + lg;
        int j = lds_j[w * 32 + rowin];
        float4 v = *reinterpret_cast<const float4*>(cb + (size_t)j * CODE_DIM + li * 4);
        *reinterpret_cast<float4*>(out + (size_t)(wavebase + rowin) * CODE_DIM + li * 4) = v;
    }
}

__global__ void finalize_kernel(const unsigned int* __restrict__ counts,
                                const float* __restrict__ loss_sum,
                                float* __restrict__ out)
{
    __shared__ float red[NB_CODE];
    int t = threadIdx.x;
    float p = (float)counts[t] / (float)NROWS;
    red[t] = p * logf(p + 1e-7f);
    __syncthreads();
    for (int s = NB_CODE / 2; s > 0; s >>= 1) {
        if (t < s) red[t] += red[t + s];
        __syncthreads();
    }
    if (t == 0) {
        out[NTC + 0] = *loss_sum / (float)NTC;
        out[NTC + 1] = expf(-red[0]);
    }
}

extern "C" void kernel_launch(void* const* d_in, const int* in_sizes, int n_in,
                              void* d_out, int out_size, void* d_ws, size_t ws_size,
                              hipStream_t stream) {
    const float* x  = (const float*)d_in[0];
    const float* cb = (const float*)d_in[1];
    float* out = (float*)d_out;
    float* ws = (float*)d_ws;

    // zero real stats each call (ws not re-poisoned between replays)
    hipMemsetAsync(d_ws, 0, 1028 * sizeof(float), stream);

    prep_kernel<<<NB_CODE / 256, 256, 0, stream>>>(cb, ws);
    io1_kernel<<<NROWS / 256, 512, 0, stream>>>(x, cb, ws, out);   // probe: pure I/O
    io2_kernel<<<NROWS / 256, 512, 0, stream>>>(x, cb, ws, out);   // probe: I/O + atomics
    vq_kernel<<<NROWS / 256, 512, 0, stream>>>(x, cb, ws, out);    // real (overwrites out)
    finalize_kernel<<<1, NB_CODE, 0, stream>>>((unsigned int*)ws, ws + W_LOSS, out);
}